// Round 3
// baseline (707.938 us; speedup 1.0000x reference)
//
#include <hip/hip_runtime.h>

// ---------------- problem constants ----------------
#define BATCH 8
#define TLEN  4096
#define DIM   768
#define TP    4098            // TLEN padded to multiple of WS=3
#define NWIN  1366            // TP/3
#define HEADS 48
#define HD    16
#define MREAL (BATCH*TP)      // 32784 rows in the rolled/padded sequence
#define MP    32896           // MREAL padded to 257*128 (GEMM tile multiple)
#define M2    (BATCH*TLEN)    // 32768 rows for the MLP path

typedef unsigned short u16;
typedef __bf16  bf16x8  __attribute__((ext_vector_type(8)));
typedef short   short8v __attribute__((ext_vector_type(8)));
typedef float   float4v __attribute__((ext_vector_type(4)));
typedef u16     u16x4   __attribute__((ext_vector_type(4)));

static __device__ __forceinline__ float bf2f(u16 u) {
  unsigned int x = ((unsigned int)u) << 16;
  return __builtin_bit_cast(float, x);
}
static __device__ __forceinline__ u16 f2bf(float f) {  // round-nearest-even
  unsigned int x = __builtin_bit_cast(unsigned int, f);
  x += 0x7fffu + ((x >> 16) & 1u);
  return (u16)(x >> 16);
}

static __device__ __forceinline__ float4v mfma_bf16(short8v a, short8v b, float4v c) {
  return __builtin_amdgcn_mfma_f32_16x16x32_bf16(
      __builtin_bit_cast(bf16x8, a), __builtin_bit_cast(bf16x8, b), c, 0, 0, 0);
}

static __device__ __forceinline__ void gload_lds16(const u16* src, u16* ldsdst) {
  __builtin_amdgcn_global_load_lds(
      (const __attribute__((address_space(1))) void*)src,
      (__attribute__((address_space(3))) void*)ldsdst,
      16, 0, 0);
}

// ---------------- weight convert + transpose: w[K][N] fp32 -> wt[N][K] bf16 ----
__global__ __launch_bounds__(256) void cvt_transpose(const float* __restrict__ w,
                                                     u16* __restrict__ wt,
                                                     int K, int N) {
  int idx = blockIdx.x * 256 + threadIdx.x;
  if (idx >= K * N) return;
  int k = idx / N, n = idx - k * N;
  wt[(size_t)n * K + k] = f2bf(w[idx]);
}

// ---------------- LayerNorm (wave per row). ROLL: build xs = roll(pad(LN(x)),-1) ----
template<bool ROLL>
__global__ __launch_bounds__(256) void ln_kernel(const float* __restrict__ x,
                                                 const float* __restrict__ g,
                                                 const float* __restrict__ bet,
                                                 u16* __restrict__ out) {
  int wave = threadIdx.x >> 6, lane = threadIdx.x & 63;
  int row = blockIdx.x * 4 + wave;
  u16* orow = out + (size_t)row * DIM;

  const float* src;
  if (ROLL) {
    bool zero = (row >= MREAL);
    int t = 0, b = 0;
    if (!zero) {
      b = row / TP;
      int m = row - b * TP;
      t = m + 1; if (t == TP) t = 0;      // xs[m] = xp[(m+1) % TP]
      if (t >= TLEN) zero = true;         // xp pad rows are exact zeros
    }
    if (zero) {
      u16x4 z = {};
#pragma unroll
      for (int c = 0; c < 3; ++c) *(u16x4*)&orow[c * 256 + lane * 4] = z;
      return;
    }
    src = x + ((size_t)b * TLEN + t) * DIM;
  } else {
    src = x + (size_t)row * DIM;
  }

  float v[12];
  float s = 0.f, s2 = 0.f;
#pragma unroll
  for (int c = 0; c < 3; ++c) {
    float4v f = *(const float4v*)&src[c * 256 + lane * 4];
#pragma unroll
    for (int q = 0; q < 4; ++q) { v[c * 4 + q] = f[q]; s += f[q]; s2 += f[q] * f[q]; }
  }
#pragma unroll
  for (int off = 1; off < 64; off <<= 1) {
    s  += __shfl_xor(s, off);
    s2 += __shfl_xor(s2, off);
  }
  float mean = s * (1.f / DIM);
  float var  = s2 * (1.f / DIM) - mean * mean;
  float rs   = rsqrtf(var + 1e-5f);
#pragma unroll
  for (int c = 0; c < 3; ++c) {
    int col = c * 256 + lane * 4;
    float4v gv = *(const float4v*)&g[col];
    float4v bv = *(const float4v*)&bet[col];
    u16x4 o4;
#pragma unroll
    for (int q = 0; q < 4; ++q) o4[q] = f2bf((v[c * 4 + q] - mean) * rs * gv[q] + bv[q]);
    *(u16x4*)&orow[col] = o4;
  }
}

// ---------------- window attention: one thread per (window, head) ----------------
__global__ __launch_bounds__(256) void attn_kernel(const u16* __restrict__ qkv,
                                                   u16* __restrict__ o) {
  int gid = blockIdx.x * 256 + threadIdx.x;   // grid sized exactly
  int h = gid % HEADS;
  int w = gid / HEADS;
  int b = w / NWIN, wl = w - b * NWIN;
  size_t row0 = (size_t)b * TP + (size_t)wl * 3;

  float q[3][HD], k[3][HD];
#pragma unroll
  for (int t = 0; t < 3; ++t) {
    const u16* rp = qkv + (row0 + t) * (3 * DIM) + h * HD;
    short8v q0 = *(const short8v*)(rp);
    short8v q1 = *(const short8v*)(rp + 8);
    short8v k0 = *(const short8v*)(rp + DIM);
    short8v k1 = *(const short8v*)(rp + DIM + 8);
#pragma unroll
    for (int d = 0; d < 8; ++d) {
      q[t][d] = bf2f((u16)q0[d]); q[t][d + 8] = bf2f((u16)q1[d]);
      k[t][d] = bf2f((u16)k0[d]); k[t][d + 8] = bf2f((u16)k1[d]);
    }
  }
  float p[3][3];
#pragma unroll
  for (int i = 0; i < 3; ++i)
#pragma unroll
    for (int j = 0; j < 3; ++j) {
      float s = 0.f;
#pragma unroll
      for (int d = 0; d < HD; ++d) s += q[i][d] * k[j][d];
      p[i][j] = s * 0.25f;                 // HD^-0.5
    }
#pragma unroll
  for (int i = 0; i < 3; ++i) {
    float mx = fmaxf(p[i][0], fmaxf(p[i][1], p[i][2]));
    float e0 = __expf(p[i][0] - mx), e1 = __expf(p[i][1] - mx), e2 = __expf(p[i][2] - mx);
    float inv = 1.f / (e0 + e1 + e2);
    p[i][0] = e0 * inv; p[i][1] = e1 * inv; p[i][2] = e2 * inv;
  }
  float acc[3][HD];
#pragma unroll
  for (int i = 0; i < 3; ++i)
#pragma unroll
    for (int d = 0; d < HD; ++d) acc[i][d] = 0.f;
#pragma unroll
  for (int t = 0; t < 3; ++t) {
    const u16* rp = qkv + (row0 + t) * (3 * DIM) + 2 * DIM + h * HD;
    short8v v0 = *(const short8v*)(rp);
    short8v v1 = *(const short8v*)(rp + 8);
#pragma unroll
    for (int d = 0; d < 8; ++d) {
      float a = bf2f((u16)v0[d]), bb = bf2f((u16)v1[d]);
#pragma unroll
      for (int i = 0; i < 3; ++i) { acc[i][d] += p[i][t] * a; acc[i][d + 8] += p[i][t] * bb; }
    }
  }
#pragma unroll
  for (int i = 0; i < 3; ++i) {
    u16 tmp[HD];
#pragma unroll
    for (int d = 0; d < HD; ++d) tmp[d] = f2bf(acc[i][d]);
    u16* op = o + (row0 + i) * DIM + h * HD;
    *(short8v*)op = *(short8v*)tmp;
    *(short8v*)(op + 8) = *(short8v*)(tmp + 8);
  }
}

// ---------------- 128x128 MFMA GEMM, prefetch double-buffer + XOR swizzle -------
// A[M][K] bf16, Bt[N][K] bf16. 256 threads = 4 waves (2M x 2N).
// LDS tile [128][64] u16 (16 KiB), XOR-swizzled: byte ^= ((row&7)<<4), applied
// via pre-swizzled global source (linear global_load_lds dest) + swizzled ds_read.
// One __syncthreads per K-step; next tile's loads issued before current compute.
// EPI 0: C bf16 plain    1: proj -> out = x + scatter(roll)   2: bias+ReLU bf16
// EPI 3: out[idx] += acc + bias  (residual already in out)
template<int EPI>
__global__ __launch_bounds__(256) void gemm128(const u16* __restrict__ A,
                                               const u16* __restrict__ Bt,
                                               int M, int N, int K,
                                               u16* __restrict__ outb,
                                               float* __restrict__ outf,
                                               const float* __restrict__ resid,
                                               const float* __restrict__ bias) {
  __shared__ u16 As[2][128 * 64];
  __shared__ u16 Bs[2][128 * 64];
  int tid = threadIdx.x;
  int wave = tid >> 6, lane = tid & 63;
  int tn = blockIdx.x, tm = blockIdx.y;
  int wm = wave >> 1, wn = wave & 1;

  float4v acc[4][4];
#pragma unroll
  for (int i = 0; i < 4; ++i)
#pragma unroll
    for (int j = 0; j < 4; ++j) acc[i][j] = (float4v){0.f, 0.f, 0.f, 0.f};

  const int arow0 = tm * 128, brow0 = tn * 128;
  const int r = lane & 15, gq = lane >> 4;

  // staging precompute: 4 chunks of 4 KiB; linear LDS dest d = c*4096 + tid*16 B,
  // global source column pre-swizzled with the inverse (same) XOR.
  int srow[4], scol[4];
#pragma unroll
  for (int c = 0; c < 4; ++c) {
    int d = c * 4096 + tid * 16;                 // dest byte offset in tile
    srow[c] = d >> 7;                            // tile row (stride 128 B)
    scol[c] = (((d & 127) ^ ((srow[c] & 7) << 4)) >> 1);  // src col (elements)
  }

  // fragment-read swizzled K-offsets (elements); row&7 == r&7 (bases mult of 16)
  const int kx0 = (((gq * 16) ^ ((r & 7) << 4)) >> 1);        // kk = 0
  const int kx1 = (((64 + gq * 16) ^ ((r & 7) << 4)) >> 1);   // kk = 1
  const int rA = wm * 64 + r, rB = wn * 64 + r;

  const int NT = K >> 6;

  auto stage = [&](int buf, int tk) {
#pragma unroll
    for (int c = 0; c < 4; ++c) {
      gload_lds16(A  + (size_t)(arow0 + srow[c]) * K + tk * 64 + scol[c],
                  &As[buf][0] + c * 2048 + tid * 8);
      gload_lds16(Bt + (size_t)(brow0 + srow[c]) * K + tk * 64 + scol[c],
                  &Bs[buf][0] + c * 2048 + tid * 8);
    }
  };

  stage(0, 0);
  __syncthreads();   // vmcnt(0)+lgkmcnt(0) drain: tile 0 landed

  for (int t = 0; t < NT; ++t) {
    const int cur = t & 1;
    if (t + 1 < NT) stage(cur ^ 1, t + 1);   // issue early, land by next barrier
#pragma unroll
    for (int kk = 0; kk < 2; ++kk) {
      const int kx = kk ? kx1 : kx0;
      short8v af[4], bfr[4];
#pragma unroll
      for (int i = 0; i < 4; ++i)
        af[i] = *(const short8v*)&As[cur][(rA + i * 16) * 64 + kx];
#pragma unroll
      for (int j = 0; j < 4; ++j)
        bfr[j] = *(const short8v*)&Bs[cur][(rB + j * 16) * 64 + kx];
#pragma unroll
      for (int i = 0; i < 4; ++i)
#pragma unroll
        for (int j = 0; j < 4; ++j)
          acc[i][j] = mfma_bf16(af[i], bfr[j], acc[i][j]);
    }
    __syncthreads();   // drains vmcnt(0): tile t+1 landed; buffers safe to flip
  }

  // epilogue: D mapping col=lane&15, row=(lane>>4)*4+reg  [m89-verified]
#pragma unroll
  for (int i = 0; i < 4; ++i) {
#pragma unroll
    for (int j = 0; j < 4; ++j) {
      int colg = brow0 + wn * 64 + j * 16 + r;
      int rowb = arow0 + wm * 64 + i * 16 + gq * 4;
#pragma unroll
      for (int v = 0; v < 4; ++v) {
        int rg = rowb + v;
        float val = acc[i][j][v];
        if constexpr (EPI == 0) {
          outb[(size_t)rg * N + colg] = f2bf(val);
        } else if constexpr (EPI == 1) {
          if (rg < MREAL) {
            int b = rg / TP, m = rg - b * TP;
            int t = m + 1; if (t == TP) t = 0;
            if (t < TLEN) {
              size_t idx = ((size_t)b * TLEN + t) * DIM + colg;
              outf[idx] = resid[idx] + val;
            }
          }
        } else if constexpr (EPI == 2) {
          float z = val + bias[colg];
          outb[(size_t)rg * N + colg] = f2bf(z > 0.f ? z : 0.f);
        } else {
          size_t idx = (size_t)rg * N + colg;
          outf[idx] = outf[idx] + val + bias[colg];
        }
      }
    }
  }
}

// ---------------- host ----------------
extern "C" void kernel_launch(void* const* d_in, const int* in_sizes, int n_in,
                              void* d_out, int out_size, void* d_ws, size_t ws_size,
                              hipStream_t stream) {
  const float* x      = (const float*)d_in[0];
  const float* g1     = (const float*)d_in[1];
  const float* b1     = (const float*)d_in[2];
  const float* w_qkv  = (const float*)d_in[3];
  const float* w_proj = (const float*)d_in[4];
  const float* g2     = (const float*)d_in[5];
  const float* b2     = (const float*)d_in[6];
  const float* w_mlp1 = (const float*)d_in[7];
  const float* b_mlp1 = (const float*)d_in[8];
  const float* w_mlp2 = (const float*)d_in[9];
  const float* b_mlp2 = (const float*)d_in[10];
  float* out = (float*)d_out;

  // workspace layout (~262 MB total)
  u16* xs     = (u16*)d_ws;                        // MP*768 bf16 (LN1, rolled/padded)
  u16* qkv    = xs     + (size_t)MP * DIM;         // MP*2304 bf16
  u16* obuf   = qkv    + (size_t)MP * 3 * DIM;     // MP*768 bf16 (attn out)
  u16* wqkvT  = obuf   + (size_t)MP * DIM;         // [2304][768]
  u16* wprojT = wqkvT  + (size_t)3 * DIM * DIM;    // [768][768]
  u16* wm1T   = wprojT + (size_t)DIM * DIM;        // [1536][768]
  u16* wm2T   = wm1T   + (size_t)2 * DIM * DIM;    // [768][1536]
  u16* ln2o = xs;    // reuse: M2*768
  u16* h1   = qkv;   // reuse: M2*1536

  cvt_transpose<<<(DIM * 3 * DIM + 255) / 256, 256, 0, stream>>>(w_qkv,  wqkvT,  DIM,     3 * DIM);
  cvt_transpose<<<(DIM * DIM + 255)     / 256, 256, 0, stream>>>(w_proj, wprojT, DIM,     DIM);
  cvt_transpose<<<(DIM * 2 * DIM + 255) / 256, 256, 0, stream>>>(w_mlp1, wm1T,   DIM,     2 * DIM);
  cvt_transpose<<<(2 * DIM * DIM + 255) / 256, 256, 0, stream>>>(w_mlp2, wm2T,   2 * DIM, DIM);

  ln_kernel<true><<<MP / 4, 256, 0, stream>>>(x, g1, b1, xs);

  gemm128<0><<<dim3(3 * DIM / 128, MP / 128), 256, 0, stream>>>(
      xs, wqkvT, MP, 3 * DIM, DIM, qkv, nullptr, nullptr, nullptr);

  attn_kernel<<<(BATCH * NWIN * HEADS) / 256, 256, 0, stream>>>(qkv, obuf);

  gemm128<1><<<dim3(DIM / 128, MP / 128), 256, 0, stream>>>(
      obuf, wprojT, MP, DIM, DIM, nullptr, out, x, nullptr);

  ln_kernel<false><<<M2 / 4, 256, 0, stream>>>(out, g2, b2, ln2o);

  gemm128<2><<<dim3(2 * DIM / 128, M2 / 128), 256, 0, stream>>>(
      ln2o, wm1T, M2, 2 * DIM, DIM, h1, nullptr, nullptr, b_mlp1);

  gemm128<3><<<dim3(DIM / 128, M2 / 128), 256, 0, stream>>>(
      h1, wm2T, M2, DIM, 2 * DIM, nullptr, out, nullptr, b_mlp2);
}

// Round 4
// 535.902 us; speedup vs baseline: 1.3210x; 1.3210x over previous
//
#include <hip/hip_runtime.h>

// ---------------- problem constants ----------------
#define BATCH 8
#define TLEN  4096
#define DIM   768
#define TP    4098            // TLEN padded to multiple of WS=3
#define NWIN  1366            // TP/3
#define HEADS 48
#define HD    16
#define MREAL (BATCH*TP)      // 32784 rows in the rolled/padded sequence
#define MP    32896           // MREAL padded to 257*128 (GEMM tile multiple)
#define M2    (BATCH*TLEN)    // 32768 rows for the MLP path

typedef unsigned short u16;
typedef __bf16  bf16x8  __attribute__((ext_vector_type(8)));
typedef short   short8v __attribute__((ext_vector_type(8)));
typedef float   float4v __attribute__((ext_vector_type(4)));
typedef u16     u16x4   __attribute__((ext_vector_type(4)));

static __device__ __forceinline__ float bf2f(u16 u) {
  unsigned int x = ((unsigned int)u) << 16;
  return __builtin_bit_cast(float, x);
}
static __device__ __forceinline__ u16 f2bf(float f) {  // round-nearest-even
  unsigned int x = __builtin_bit_cast(unsigned int, f);
  x += 0x7fffu + ((x >> 16) & 1u);
  return (u16)(x >> 16);
}

static __device__ __forceinline__ float4v mfma_bf16(short8v a, short8v b, float4v c) {
  return __builtin_amdgcn_mfma_f32_16x16x32_bf16(
      __builtin_bit_cast(bf16x8, a), __builtin_bit_cast(bf16x8, b), c, 0, 0, 0);
}

static __device__ __forceinline__ void gload_lds16(const u16* src, u16* ldsdst) {
  __builtin_amdgcn_global_load_lds(
      (const __attribute__((address_space(1))) void*)src,
      (__attribute__((address_space(3))) void*)ldsdst,
      16, 0, 0);
}

// ---------------- weight convert + transpose: w[K][N] fp32 -> wt[N][K] bf16 ----
__global__ __launch_bounds__(256) void cvt_transpose(const float* __restrict__ w,
                                                     u16* __restrict__ wt,
                                                     int K, int N) {
  int idx = blockIdx.x * 256 + threadIdx.x;
  if (idx >= K * N) return;
  int k = idx / N, n = idx - k * N;
  wt[(size_t)n * K + k] = f2bf(w[idx]);
}

// ---------------- LayerNorm fp32-in (wave per row). ROLL: xs = roll(pad(LN(x)),-1) ----
template<bool ROLL>
__global__ __launch_bounds__(256) void ln_kernel(const float* __restrict__ x,
                                                 const float* __restrict__ g,
                                                 const float* __restrict__ bet,
                                                 u16* __restrict__ out) {
  int wave = threadIdx.x >> 6, lane = threadIdx.x & 63;
  int row = blockIdx.x * 4 + wave;
  u16* orow = out + (size_t)row * DIM;

  const float* src;
  if (ROLL) {
    bool zero = (row >= MREAL);
    int t = 0, b = 0;
    if (!zero) {
      b = row / TP;
      int m = row - b * TP;
      t = m + 1; if (t == TP) t = 0;      // xs[m] = xp[(m+1) % TP]
      if (t >= TLEN) zero = true;         // xp pad rows are exact zeros
    }
    if (zero) {
      u16x4 z = {};
#pragma unroll
      for (int c = 0; c < 3; ++c) *(u16x4*)&orow[c * 256 + lane * 4] = z;
      return;
    }
    src = x + ((size_t)b * TLEN + t) * DIM;
  } else {
    src = x + (size_t)row * DIM;
  }

  float v[12];
  float s = 0.f, s2 = 0.f;
#pragma unroll
  for (int c = 0; c < 3; ++c) {
    float4v f = *(const float4v*)&src[c * 256 + lane * 4];
#pragma unroll
    for (int q = 0; q < 4; ++q) { v[c * 4 + q] = f[q]; s += f[q]; s2 += f[q] * f[q]; }
  }
#pragma unroll
  for (int off = 1; off < 64; off <<= 1) {
    s  += __shfl_xor(s, off);
    s2 += __shfl_xor(s2, off);
  }
  float mean = s * (1.f / DIM);
  float var  = s2 * (1.f / DIM) - mean * mean;
  float rs   = rsqrtf(var + 1e-5f);
#pragma unroll
  for (int c = 0; c < 3; ++c) {
    int col = c * 256 + lane * 4;
    float4v gv = *(const float4v*)&g[col];
    float4v bv = *(const float4v*)&bet[col];
    u16x4 o4;
#pragma unroll
    for (int q = 0; q < 4; ++q) o4[q] = f2bf((v[c * 4 + q] - mean) * rs * gv[q] + bv[q]);
    *(u16x4*)&orow[col] = o4;
  }
}

// ---------------- LayerNorm bf16-in (wave per row), rows = M2 ----------------
__global__ __launch_bounds__(256) void lnb_kernel(const u16* __restrict__ xin,
                                                  const float* __restrict__ g,
                                                  const float* __restrict__ bet,
                                                  u16* __restrict__ out) {
  int wave = threadIdx.x >> 6, lane = threadIdx.x & 63;
  int row = blockIdx.x * 4 + wave;
  const u16* src = xin + (size_t)row * DIM;
  u16* orow = out + (size_t)row * DIM;

  float v[12];
  float s = 0.f, s2 = 0.f;
#pragma unroll
  for (int c = 0; c < 3; ++c) {
    u16x4 h = *(const u16x4*)&src[c * 256 + lane * 4];
#pragma unroll
    for (int q = 0; q < 4; ++q) {
      float f = bf2f(h[q]);
      v[c * 4 + q] = f; s += f; s2 += f * f;
    }
  }
#pragma unroll
  for (int off = 1; off < 64; off <<= 1) {
    s  += __shfl_xor(s, off);
    s2 += __shfl_xor(s2, off);
  }
  float mean = s * (1.f / DIM);
  float var  = s2 * (1.f / DIM) - mean * mean;
  float rs   = rsqrtf(var + 1e-5f);
#pragma unroll
  for (int c = 0; c < 3; ++c) {
    int col = c * 256 + lane * 4;
    float4v gv = *(const float4v*)&g[col];
    float4v bv = *(const float4v*)&bet[col];
    u16x4 o4;
#pragma unroll
    for (int q = 0; q < 4; ++q) o4[q] = f2bf((v[c * 4 + q] - mean) * rs * gv[q] + bv[q]);
    *(u16x4*)&orow[col] = o4;
  }
}

// ---------------- window attention: one thread per (window, head) ----------------
__global__ __launch_bounds__(256) void attn_kernel(const u16* __restrict__ qkv,
                                                   u16* __restrict__ o) {
  int gid = blockIdx.x * 256 + threadIdx.x;   // grid sized exactly
  int h = gid % HEADS;
  int w = gid / HEADS;
  int b = w / NWIN, wl = w - b * NWIN;
  size_t row0 = (size_t)b * TP + (size_t)wl * 3;

  float q[3][HD], k[3][HD];
#pragma unroll
  for (int t = 0; t < 3; ++t) {
    const u16* rp = qkv + (row0 + t) * (3 * DIM) + h * HD;
    short8v q0 = *(const short8v*)(rp);
    short8v q1 = *(const short8v*)(rp + 8);
    short8v k0 = *(const short8v*)(rp + DIM);
    short8v k1 = *(const short8v*)(rp + DIM + 8);
#pragma unroll
    for (int d = 0; d < 8; ++d) {
      q[t][d] = bf2f((u16)q0[d]); q[t][d + 8] = bf2f((u16)q1[d]);
      k[t][d] = bf2f((u16)k0[d]); k[t][d + 8] = bf2f((u16)k1[d]);
    }
  }
  float p[3][3];
#pragma unroll
  for (int i = 0; i < 3; ++i)
#pragma unroll
    for (int j = 0; j < 3; ++j) {
      float s = 0.f;
#pragma unroll
      for (int d = 0; d < HD; ++d) s += q[i][d] * k[j][d];
      p[i][j] = s * 0.25f;                 // HD^-0.5
    }
#pragma unroll
  for (int i = 0; i < 3; ++i) {
    float mx = fmaxf(p[i][0], fmaxf(p[i][1], p[i][2]));
    float e0 = __expf(p[i][0] - mx), e1 = __expf(p[i][1] - mx), e2 = __expf(p[i][2] - mx);
    float inv = 1.f / (e0 + e1 + e2);
    p[i][0] = e0 * inv; p[i][1] = e1 * inv; p[i][2] = e2 * inv;
  }
  float acc[3][HD];
#pragma unroll
  for (int i = 0; i < 3; ++i)
#pragma unroll
    for (int d = 0; d < HD; ++d) acc[i][d] = 0.f;
#pragma unroll
  for (int t = 0; t < 3; ++t) {
    const u16* rp = qkv + (row0 + t) * (3 * DIM) + 2 * DIM + h * HD;
    short8v v0 = *(const short8v*)(rp);
    short8v v1 = *(const short8v*)(rp + 8);
#pragma unroll
    for (int d = 0; d < 8; ++d) {
      float a = bf2f((u16)v0[d]), bb = bf2f((u16)v1[d]);
#pragma unroll
      for (int i = 0; i < 3; ++i) { acc[i][d] += p[i][t] * a; acc[i][d + 8] += p[i][t] * bb; }
    }
  }
#pragma unroll
  for (int i = 0; i < 3; ++i) {
    u16 tmp[HD];
#pragma unroll
    for (int d = 0; d < HD; ++d) tmp[d] = f2bf(acc[i][d]);
    u16* op = o + (row0 + i) * DIM + h * HD;
    *(short8v*)op = *(short8v*)tmp;
    *(short8v*)(op + 8) = *(short8v*)(tmp + 8);
  }
}

// ---------------- 128x128 MFMA GEMM, 8 waves (4Mx2N grid -> wave tile 64x32) ----
// A[M][K] bf16, Bt[N][K] bf16. 512 threads; single-buffered 32 KiB LDS ->
// 3 blocks/CU (24 waves/CU) for latency hiding. XOR swizzle byte^=((row&7)<<4)
// via pre-swizzled global source (linear global_load_lds dest) + swizzled ds_read.
// EPI 0: C bf16 plain
// EPI 1: resf bf16 = x + scatter(roll)   (outb=resf, residf=x)
// EPI 2: bias+ReLU bf16
// EPI 3: out fp32 = resf + acc + bias    (outf=out, residb=resf)
template<int EPI>
__global__ __launch_bounds__(512, 6) void gemm8w(const u16* __restrict__ A,
                                                 const u16* __restrict__ Bt,
                                                 int N, int K,
                                                 u16* __restrict__ outb,
                                                 float* __restrict__ outf,
                                                 const float* __restrict__ residf,
                                                 const u16* __restrict__ residb,
                                                 const float* __restrict__ bias) {
  __shared__ u16 As[128 * 64];
  __shared__ u16 Bs[128 * 64];
  const int tid = threadIdx.x;
  const int wave = tid >> 6, lane = tid & 63;
  const int wm = wave >> 2, wn = wave & 3;          // 2 M-waves x 4 N-waves
  const int r = lane & 15, gq = lane >> 4;

  // bijective XCD chunk swizzle (m204) on linearized bid (x fastest)
  const int nwg = gridDim.x, gx = N >> 7;
  int wg = blockIdx.x;
  int qd = nwg >> 3, rr = nwg & 7, xcd = wg & 7, lid = wg >> 3;
  int swz = (xcd < rr ? xcd * (qd + 1) : rr * (qd + 1) + (xcd - rr) * qd) + lid;
  const int tm = swz / gx, tn = swz - tm * gx;
  const int arow0 = tm * 128, brow0 = tn * 128;

  // staging precompute: 2 chunks of 8 KiB per matrix; linear LDS dest
  // d = c*8192 + tid*16 bytes, global source column pre-swizzled (same XOR).
  int srow[2], scol[2];
#pragma unroll
  for (int c = 0; c < 2; ++c) {
    int d = c * 8192 + tid * 16;
    srow[c] = d >> 7;
    scol[c] = (((d & 127) ^ ((srow[c] & 7) << 4)) >> 1);
  }

  // fragment-read swizzled K-offsets (elements); row&7 == r&7 (bases mult of 16)
  const int kx0 = (((gq * 16) ^ ((r & 7) << 4)) >> 1);        // kk = 0
  const int kx1 = (((64 + gq * 16) ^ ((r & 7) << 4)) >> 1);   // kk = 1
  const int rA = wm * 64 + r, rB = wn * 32 + r;

  float4v acc[4][2];
#pragma unroll
  for (int i = 0; i < 4; ++i)
#pragma unroll
    for (int j = 0; j < 2; ++j) acc[i][j] = (float4v){0.f, 0.f, 0.f, 0.f};

  const int NT = K >> 6;
  for (int t = 0; t < NT; ++t) {
    const int k0 = t << 6;
#pragma unroll
    for (int c = 0; c < 2; ++c) {
      gload_lds16(A  + (size_t)(arow0 + srow[c]) * K + k0 + scol[c],
                  &As[0] + c * 4096 + tid * 8);
      gload_lds16(Bt + (size_t)(brow0 + srow[c]) * K + k0 + scol[c],
                  &Bs[0] + c * 4096 + tid * 8);
    }
    __syncthreads();   // drains vmcnt(0): tile landed
#pragma unroll
    for (int kk = 0; kk < 2; ++kk) {
      const int kx = kk ? kx1 : kx0;
      short8v af[4], bfr[2];
#pragma unroll
      for (int i = 0; i < 4; ++i)
        af[i] = *(const short8v*)&As[(rA + i * 16) * 64 + kx];
#pragma unroll
      for (int j = 0; j < 2; ++j)
        bfr[j] = *(const short8v*)&Bs[(rB + j * 16) * 64 + kx];
#pragma unroll
      for (int i = 0; i < 4; ++i)
#pragma unroll
        for (int j = 0; j < 2; ++j)
          acc[i][j] = mfma_bf16(af[i], bfr[j], acc[i][j]);
    }
    __syncthreads();   // safe to overwrite buffer
  }

  // epilogue: D mapping col=lane&15, row=(lane>>4)*4+reg  [m89-verified]
#pragma unroll
  for (int i = 0; i < 4; ++i) {
#pragma unroll
    for (int j = 0; j < 2; ++j) {
      int colg = brow0 + wn * 32 + j * 16 + r;
      int rowb = arow0 + wm * 64 + i * 16 + gq * 4;
#pragma unroll
      for (int v = 0; v < 4; ++v) {
        int rg = rowb + v;
        float val = acc[i][j][v];
        if constexpr (EPI == 0) {
          outb[(size_t)rg * N + colg] = f2bf(val);
        } else if constexpr (EPI == 1) {
          if (rg < MREAL) {
            int b = rg / TP, m = rg - b * TP;
            int t = m + 1; if (t == TP) t = 0;
            if (t < TLEN) {
              size_t idx = ((size_t)b * TLEN + t) * DIM + colg;
              outb[idx] = f2bf(residf[idx] + val);
            }
          }
        } else if constexpr (EPI == 2) {
          float z = val + bias[colg];
          outb[(size_t)rg * N + colg] = f2bf(z > 0.f ? z : 0.f);
        } else {
          size_t idx = (size_t)rg * N + colg;
          outf[idx] = bf2f(residb[idx]) + val + bias[colg];
        }
      }
    }
  }
}

// ---------------- host ----------------
extern "C" void kernel_launch(void* const* d_in, const int* in_sizes, int n_in,
                              void* d_out, int out_size, void* d_ws, size_t ws_size,
                              hipStream_t stream) {
  const float* x      = (const float*)d_in[0];
  const float* g1     = (const float*)d_in[1];
  const float* b1     = (const float*)d_in[2];
  const float* w_qkv  = (const float*)d_in[3];
  const float* w_proj = (const float*)d_in[4];
  const float* g2     = (const float*)d_in[5];
  const float* b2     = (const float*)d_in[6];
  const float* w_mlp1 = (const float*)d_in[7];
  const float* b_mlp1 = (const float*)d_in[8];
  const float* w_mlp2 = (const float*)d_in[9];
  const float* b_mlp2 = (const float*)d_in[10];
  float* out = (float*)d_out;

  // workspace layout (~262 MB total)
  u16* xs     = (u16*)d_ws;                        // MP*768 bf16 (LN1, rolled/padded)
  u16* qkv    = xs     + (size_t)MP * DIM;         // MP*2304 bf16
  u16* obuf   = qkv    + (size_t)MP * 3 * DIM;     // MP*768 bf16 (attn out)
  u16* wqkvT  = obuf   + (size_t)MP * DIM;         // [2304][768]
  u16* wprojT = wqkvT  + (size_t)3 * DIM * DIM;    // [768][768]
  u16* wm1T   = wprojT + (size_t)DIM * DIM;        // [1536][768]
  u16* wm2T   = wm1T   + (size_t)2 * DIM * DIM;    // [768][1536]
  // region reuse across the pipeline (each producer runs after the consumer
  // of the previous tenant):
  u16* resf = xs;    // M2*768  bf16 residual trunk (xs dead after QKV GEMM)
  u16* ln2o = obuf;  // M2*768  (obuf dead after proj GEMM)
  u16* h1   = qkv;   // M2*1536 (qkv dead after attn)

  cvt_transpose<<<(DIM * 3 * DIM + 255) / 256, 256, 0, stream>>>(w_qkv,  wqkvT,  DIM,     3 * DIM);
  cvt_transpose<<<(DIM * DIM + 255)     / 256, 256, 0, stream>>>(w_proj, wprojT, DIM,     DIM);
  cvt_transpose<<<(DIM * 2 * DIM + 255) / 256, 256, 0, stream>>>(w_mlp1, wm1T,   DIM,     2 * DIM);
  cvt_transpose<<<(2 * DIM * DIM + 255) / 256, 256, 0, stream>>>(w_mlp2, wm2T,   2 * DIM, DIM);

  ln_kernel<true><<<MP / 4, 256, 0, stream>>>(x, g1, b1, xs);

  gemm8w<0><<<(MP / 128) * (3 * DIM / 128), 512, 0, stream>>>(
      xs, wqkvT, 3 * DIM, DIM, qkv, nullptr, nullptr, nullptr, nullptr);

  attn_kernel<<<(BATCH * NWIN * HEADS) / 256, 256, 0, stream>>>(qkv, obuf);

  // proj: resf = bf16(x + scatter(attn @ w_proj))
  gemm8w<1><<<(MP / 128) * (DIM / 128), 512, 0, stream>>>(
      obuf, wprojT, DIM, DIM, resf, nullptr, x, nullptr, nullptr);

  lnb_kernel<<<M2 / 4, 256, 0, stream>>>(resf, g2, b2, ln2o);

  gemm8w<2><<<(M2 / 128) * (2 * DIM / 128), 512, 0, stream>>>(
      ln2o, wm1T, 2 * DIM, DIM, h1, nullptr, nullptr, nullptr, b_mlp1);

  // mlp2: out(fp32) = resf + h1 @ w_mlp2 + b
  gemm8w<3><<<(M2 / 128) * (DIM / 128), 512, 0, stream>>>(
      h1, wm2T, DIM, 2 * DIM, nullptr, out, nullptr, resf, b_mlp2);
}